// Round 6
// baseline (89.768 us; speedup 1.0000x reference)
//
#include <hip/hip_runtime.h>
#include <stdint.h>

// LIF neuron scan: B=16, S=2048, D=1024, fp32. NUMERICS FROZEN (absmax 0.0):
// XLA-contracted fp32 — __builtin_fmaf at syn/mem/tha sites, contract(off)
// elsewhere. DO NOT change step().
//
// R5 post-mortem: producer wave couldn't hold 16 float4 in 68 VGPRs -> staging
// serialized on HBM latency; barriers coupled consumer to it (88us).
// R6: single wave per block + async global_load_lds (width 16) staging:
//   - no producer, no barriers, no VGPR round-trip
//   - double-buffered 64t x 64d LDS tiles, 16 DMA instrs per tile
//   - counted vmcnt (never 0): queue at wait = [loads k:16][stores k-1:64]
//     [loads k+1:16]; vmcnt retires in order, so vmcnt(32) == "loads k done".
//   - LDS reads lds[t][lane]: 2 lanes/bank = conflict-free; groups of 16
//     prefetched one group ahead to hide ds_read latency.

#define SB 16
#define SS 2048
#define SD 1024
#define TILE 64
#define NT (SS / TILE)   // 32 tiles

typedef const __attribute__((address_space(1))) void* gas_ptr;
typedef __attribute__((address_space(3))) void* las_ptr;

__global__ __launch_bounds__(64, 1) void lif_kernel(
    const float* __restrict__ x,
    const float* __restrict__ beta_mem_p,
    const float* __restrict__ beta_syn_p,
    const float* __restrict__ adapt_p,
    const float* __restrict__ scale_p,
    const float* __restrict__ lth_p,
    float* __restrict__ out)
{
#pragma clang fp contract(off)
    __shared__ __attribute__((aligned(16))) float lds[2][TILE][64];   // 32 KB

    const int bk   = blockIdx.x;           // 0..255
    const int b    = bk >> 4;              // batch
    const int d0   = (bk & 15) << 6;       // first of this block's 64 d's
    const int lane = threadIdx.x;          // 0..63
    const int d    = d0 + lane;

    // scalar/param loads first (oldest in vmcnt queue -> never over-drained)
    const float beta_mem = beta_mem_p[0];
    const float beta_syn = beta_syn_p[0];
    const float p        = adapt_p[0];
    const float scale    = scale_p[d];
    const float lth      = lth_p[d];

    const float* xb = x   + ((size_t)b * SS) * SD + d0;
    float*       sp = out + ((size_t)b * SS) * SD + d;

    // staging map: call r stages rows 4r..4r+3; lane l -> row 4r+(l>>4),
    // cols ((l&15)*4 .. +3); LDS dest = uniform base + l*16 (linear match).
    const int srow = lane >> 4;            // 0..3
    const int scol = (lane & 15) << 2;     // 0,4,...,60
    const float* src_base = xb + (size_t)srow * SD + scol;

    auto issue_tile = [&](int k) {
        const float* s0 = src_base + (size_t)(k * TILE) * SD;
        float* dst = &lds[k & 1][0][0];
        #pragma unroll
        for (int r = 0; r < 16; ++r) {
            __builtin_amdgcn_global_load_lds(
                (gas_ptr)(s0 + (size_t)(r * 4) * SD),
                (las_ptr)(dst + r * 4 * 64),
                16, 0, 0);
        }
    };

    float mem = 0.f, syn = 0.f, tha = 0.f, refr = 0.f;

    // FROZEN numerics: one timestep (XLA fma contraction replicated)
    auto step = [&](float xt, int t) {
        syn = __builtin_fmaf(beta_syn, syn, xt);
        const float nonref = (refr <= 0.f) ? 1.f : 0.f;
        mem = __builtin_fmaf(beta_mem, mem, syn * nonref);
        const float q = p * tha;
        const float cur_th = __builtin_fmaf(q, scale, lth);
        const float spike = (mem >= cur_th) ? 1.f : 0.f;
        mem = mem - spike * cur_th;
        tha = __builtin_fmaf(0.9f, tha, 0.1f * spike);
        refr = (spike > 0.5f) ? 2.0f : fmaxf(refr - 1.f, 0.f);
        sp[(size_t)t * SD] = spike;
    };

    auto rd16 = [&](float* xc, int k, int g) {
        #pragma unroll
        for (int i = 0; i < 16; ++i) xc[i] = lds[k & 1][g * 16 + i][lane];
    };

    issue_tile(0);
    issue_tile(1);
    asm volatile("s_waitcnt vmcnt(16)" ::: "memory");   // tile 0 landed

    for (int k = 0; k < NT; ++k) {
        const int t0 = k * TILE;
        float a[16], c[16];
        rd16(a, k, 0);
        rd16(c, k, 1);
        #pragma unroll
        for (int i = 0; i < 16; ++i) step(a[i], t0 + i);
        rd16(a, k, 2);
        #pragma unroll
        for (int i = 0; i < 16; ++i) step(c[i], t0 + 16 + i);
        rd16(c, k, 3);
        #pragma unroll
        for (int i = 0; i < 16; ++i) step(a[i], t0 + 32 + i);
        #pragma unroll
        for (int i = 0; i < 16; ++i) step(c[i], t0 + 48 + i);

        if (k + 2 < NT) issue_tile(k + 2);   // buffer k&1 fully read above
        if (k + 1 < NT)
            asm volatile("s_waitcnt vmcnt(32)" ::: "memory");  // tile k+1 landed
    }

    // final carry: membrane, synaptic, th_adapt, refractory (each B x D)
    const size_t base = (size_t)SB * SS * SD;
    const size_t off  = (size_t)b * SD + d;
    out[base + 0 * (size_t)SB * SD + off] = mem;
    out[base + 1 * (size_t)SB * SD + off] = syn;
    out[base + 2 * (size_t)SB * SD + off] = tha;
    out[base + 3 * (size_t)SB * SD + off] = refr;
}

extern "C" void kernel_launch(void* const* d_in, const int* in_sizes, int n_in,
                              void* d_out, int out_size, void* d_ws, size_t ws_size,
                              hipStream_t stream) {
    const float* x        = (const float*)d_in[0];
    const float* beta_mem = (const float*)d_in[1];
    const float* beta_syn = (const float*)d_in[2];
    const float* adapt_p  = (const float*)d_in[3];
    const float* scale    = (const float*)d_in[4];
    const float* lth      = (const float*)d_in[5];
    float* out = (float*)d_out;

    // 16384 chains / 64 threads = 256 blocks -> 1 wave per CU, 1 block/CU
    lif_kernel<<<256, 64, 0, stream>>>(x, beta_mem, beta_syn, adapt_p, scale, lth, out);
}

// Round 7
// 86.520 us; speedup vs baseline: 1.0375x; 1.0375x over previous
//
#include <hip/hip_runtime.h>
#include <stdint.h>

// LIF neuron scan: B=16, S=2048, D=1024, fp32. NUMERICS FROZEN (absmax 0.0):
// XLA-contracted fp32 — __builtin_fmaf at syn/mem/tha sites, contract(off)
// elsewhere. cndmask-folds below are value-identical (0*v / 1*v exact; only
// zero-sign can differ, which compares & absmax treat as equal).
//
// R6 post-mortem: 95 cy/step vs ~36 cy issue cost -> stall + VALU fat.
// R7 changes: (1) trimmed step: direct selects instead of materialized
// 0/1 floats + muls (-3..4 VALU/step); (2) stores via uniform base +
// 32-bit index (saddr form, 1 v_add/step); (3) vmcnt(16) at iteration TOP
// (waits only prior-tile stores, ~retired) instead of draining fresh
// stores at the tail; (4) whole 64-step x-tile read to registers, fenced
// with lgkmcnt(0)+sched_barrier before the DMA overwrites the buffer.

#define SB 16
#define SS 2048
#define SD 1024
#define TILE 64
#define NT (SS / TILE)   // 32 tiles

typedef const __attribute__((address_space(1))) void* gas_ptr;
typedef __attribute__((address_space(3))) void* las_ptr;

__global__ __launch_bounds__(64, 1) void lif_kernel(
    const float* __restrict__ x,
    const float* __restrict__ beta_mem_p,
    const float* __restrict__ beta_syn_p,
    const float* __restrict__ adapt_p,
    const float* __restrict__ scale_p,
    const float* __restrict__ lth_p,
    float* __restrict__ out)
{
#pragma clang fp contract(off)
    __shared__ __attribute__((aligned(16))) float lds[2][TILE][64];   // 32 KB

    const int bk   = blockIdx.x;           // 0..255
    const int b    = bk >> 4;              // batch
    const int d0   = (bk & 15) << 6;       // first of this block's 64 d's
    const int lane = threadIdx.x;          // 0..63
    const int d    = d0 + lane;

    const float beta_mem = beta_mem_p[0];
    const float beta_syn = beta_syn_p[0];
    const float p        = adapt_p[0];
    const float scale    = scale_p[d];
    const float lth      = lth_p[d];

    const float* xb   = x   + ((size_t)b * SS) * SD + d0;
    float*       outb = out + ((size_t)b * SS) * SD + d0;   // wave-uniform base

    // DMA staging map: call r stages rows 4r..4r+3; lane l -> row 4r+(l>>4),
    // cols ((l&15)*4..+3); LDS dest = uniform base + l*16 (linear match).
    const int srow = lane >> 4;            // 0..3
    const int scol = (lane & 15) << 2;     // 0,4,...,60
    const float* src_base = xb + (size_t)srow * SD + scol;

    auto issue_tile = [&](int k) {
        const float* s0 = src_base + (size_t)(k * TILE) * SD;
        float* dst = &lds[k & 1][0][0];
        #pragma unroll
        for (int r = 0; r < 16; ++r) {
            __builtin_amdgcn_global_load_lds(
                (gas_ptr)(s0 + (size_t)(r * 4) * SD),
                (las_ptr)(dst + r * 4 * 64),
                16, 0, 0);
        }
    };

    float mem = 0.f, syn = 0.f, tha = 0.f, refr = 0.f;
    int sidx = lane;                       // 32-bit store index (bytes/4)

    // FROZEN numerics, lean form. Every select is value-identical to the
    // reference's mul-by-{0,1} (see header comment).
    auto step = [&](float xt) {
        syn = __builtin_fmaf(beta_syn, syn, xt);
        const bool  nref    = (refr <= 0.f);
        const float syn_eff = nref ? syn : 0.f;            // syn * nonref
        mem = __builtin_fmaf(beta_mem, mem, syn_eff);
        const float q      = p * tha;
        const float cur_th = __builtin_fmaf(q, scale, lth);
        const bool  fired  = (mem >= cur_th);
        const float spike  = fired ? 1.f : 0.f;
        mem = mem - (fired ? cur_th : 0.f);                // mem - spike*cur_th
        tha = __builtin_fmaf(0.9f, tha, fired ? 0.1f : 0.f); // +0.1*spike
        const float rnext = fmaxf(refr - 1.f, 0.f);
        refr = fired ? 2.0f : rnext;
        outb[sidx] = spike;
        sidx += SD;
    };

    issue_tile(0);
    issue_tile(1);

    for (int k = 0; k < NT; ++k) {
        // tile k guaranteed landed: retire all but 16 newest vmem ops
        // (= last stores of tile k-1, issued >=1 tile ago -> wait ~free)
        asm volatile("s_waitcnt vmcnt(16)" ::: "memory");

        // read the whole 64-step x-tile into registers (static indexing only)
        float xa[16], xbv[16], xc[16], xd[16];
        #pragma unroll
        for (int i = 0; i < 16; ++i) xa[i]  = lds[k & 1][i][lane];
        #pragma unroll
        for (int i = 0; i < 16; ++i) xbv[i] = lds[k & 1][16 + i][lane];
        #pragma unroll
        for (int i = 0; i < 16; ++i) xc[i]  = lds[k & 1][32 + i][lane];
        #pragma unroll
        for (int i = 0; i < 16; ++i) xd[i]  = lds[k & 1][48 + i][lane];
        // LDS reads must complete before DMA reuses this buffer
        asm volatile("s_waitcnt lgkmcnt(0)" ::: "memory");
        __builtin_amdgcn_sched_barrier(0);
        if (k + 2 < NT) issue_tile(k + 2);

        #pragma unroll
        for (int i = 0; i < 16; ++i) step(xa[i]);
        #pragma unroll
        for (int i = 0; i < 16; ++i) step(xbv[i]);
        #pragma unroll
        for (int i = 0; i < 16; ++i) step(xc[i]);
        #pragma unroll
        for (int i = 0; i < 16; ++i) step(xd[i]);
    }

    // final carry: membrane, synaptic, th_adapt, refractory (each B x D)
    const size_t base = (size_t)SB * SS * SD;
    const size_t off  = (size_t)b * SD + d;
    out[base + 0 * (size_t)SB * SD + off] = mem;
    out[base + 1 * (size_t)SB * SD + off] = syn;
    out[base + 2 * (size_t)SB * SD + off] = tha;
    out[base + 3 * (size_t)SB * SD + off] = refr;
}

extern "C" void kernel_launch(void* const* d_in, const int* in_sizes, int n_in,
                              void* d_out, int out_size, void* d_ws, size_t ws_size,
                              hipStream_t stream) {
    const float* x        = (const float*)d_in[0];
    const float* beta_mem = (const float*)d_in[1];
    const float* beta_syn = (const float*)d_in[2];
    const float* adapt_p  = (const float*)d_in[3];
    const float* scale    = (const float*)d_in[4];
    const float* lth      = (const float*)d_in[5];
    float* out = (float*)d_out;

    // 16384 chains / 64 threads = 256 blocks -> 1 wave per CU, 1 block/CU
    lif_kernel<<<256, 64, 0, stream>>>(x, beta_mem, beta_syn, adapt_p, scale, lth, out);
}